// Round 9
// baseline (313.509 us; speedup 1.0000x reference)
//
#include <hip/hip_runtime.h>
#include <hip/hip_bf16.h>
#include <math.h>

// Problem constants (from reference)
#define NN   31      // tree nodes
#define VV   50000   // vocab
#define EE   128     // embed = enc = H = 128
#define HH   128
#define BB   64
#define LL   128
#define NLBL 104

// ---------------------------------------------------------------------------
// Generic fp32 GEMM: C[M,N] = A[M,128] * B[N,128]^T (+ bias[N])
// Tile 64x128, 256 threads, K split in 2 halves of 64 so LDS stays < 64KB.
// gridDim.z indexes a (B, bias, C) set -> fuses sibling GEMMs sharing A.
// ---------------------------------------------------------------------------
template <bool BIAS>
__global__ __launch_bounds__(256, 2) void gemm128(const float* __restrict__ A,
                                                  const float* __restrict__ B0,
                                                  const float* __restrict__ B1,
                                                  const float* __restrict__ bias0,
                                                  const float* __restrict__ bias1,
                                                  float* __restrict__ C0,
                                                  float* __restrict__ C1,
                                                  int M, int N) {
    const float* Bm  = blockIdx.z ? B1 : B0;
    const float* bias = blockIdx.z ? bias1 : bias0;
    float* C = blockIdx.z ? C1 : C0;

    __shared__ float4 As[64 * 17];
    __shared__ float4 Bs[128 * 17];
    const int tid = threadIdx.x;
    const int m0 = blockIdx.x * 64;
    const int n0 = blockIdx.y * 128;
    const float4* Af4 = (const float4*)A;
    const float4* Bf4 = (const float4*)Bm;

    const int r0 = (tid >> 4) * 4;
    const int cb = tid & 15;
    float acc[4][8] = {};

    for (int kk = 0; kk < 2; ++kk) {
        for (int f = tid; f < 128 * 16; f += 256) {
            int r = f >> 4, e = f & 15;
            Bs[r * 17 + e] = Bf4[(size_t)(n0 + r) * 32 + kk * 16 + e];
        }
        for (int f = tid; f < 64 * 16; f += 256) {
            int r = f >> 4, e = f & 15;
            float4 v = make_float4(0.f, 0.f, 0.f, 0.f);
            if (m0 + r < M) v = Af4[(size_t)(m0 + r) * 32 + kk * 16 + e];
            As[r * 17 + e] = v;
        }
        __syncthreads();
        #pragma unroll
        for (int e = 0; e < 16; ++e) {
            float4 a[4], b[8];
            #pragma unroll
            for (int i = 0; i < 4; ++i) a[i] = As[(r0 + i) * 17 + e];
            #pragma unroll
            for (int j = 0; j < 8; ++j) b[j] = Bs[(cb + j * 16) * 17 + e];
            #pragma unroll
            for (int i = 0; i < 4; ++i) {
                #pragma unroll
                for (int j = 0; j < 8; ++j) {
                    acc[i][j] += a[i].x * b[j].x;
                    acc[i][j] += a[i].y * b[j].y;
                    acc[i][j] += a[i].z * b[j].z;
                    acc[i][j] += a[i].w * b[j].w;
                }
            }
        }
        __syncthreads();
    }

    #pragma unroll
    for (int i = 0; i < 4; ++i) {
        int row = m0 + r0 + i;
        if (row < M) {
            #pragma unroll
            for (int j = 0; j < 8; ++j) {
                int col = n0 + cb + j * 16;
                float v = acc[i][j];
                if (BIAS) v += bias[col];
                C[(size_t)row * N + col] = v;
            }
        }
    }
}

// ---------------------------------------------------------------------------
// Tree encode: gather 31 projected rows, heap-sum in regs, node-max.
// ---------------------------------------------------------------------------
__global__ __launch_bounds__(256) void tree_encode(const int* __restrict__ tok,
                                                   const float* __restrict__ Wemb,
                                                   const float* __restrict__ Wcb,
                                                   float* __restrict__ enc) {
    __shared__ int st[2][NN];
    const int tid = threadIdx.x;
    const int p = tid >> 7;
    const int c = tid & 127;
    const int bl = blockIdx.x * 2;
    if (tid < 2 * NN) {
        int pp = tid / NN, jj = tid - pp * NN;
        st[pp][jj] = tok[(size_t)(bl + pp) * NN + jj];
    }
    __syncthreads();

    float v[NN];
    #pragma unroll
    for (int j = 0; j < NN; ++j)
        v[j] = Wemb[(size_t)st[p][j] * 128 + c];
    #pragma unroll
    for (int i = 14; i >= 0; --i)
        v[i] += v[2 * i + 1] + v[2 * i + 2];

    const float wb = Wcb[c];
    float m = v[0] + 31.f * wb;
    #pragma unroll
    for (int i = 1; i <= 2; ++i)  m = fmaxf(m, v[i] + 15.f * wb);
    #pragma unroll
    for (int i = 3; i <= 6; ++i)  m = fmaxf(m, v[i] + 7.f * wb);
    #pragma unroll
    for (int i = 7; i <= 14; ++i) m = fmaxf(m, v[i] + 3.f * wb);
    #pragma unroll
    for (int i = 15; i <= 30; ++i) m = fmaxf(m, v[i] + wb);

    enc[(size_t)(bl + p) * 128 + c] = m;
}

// ---------------------------------------------------------------------------
// GRU scan v8: fp32 end-to-end (v7's f16 weights FAILED at absmax 1.17e-2:
// weight quantization is a persistent model perturbation -> error grows
// ~linearly over the 128-step recurrence; 16-bit weights are out).
// Structure: 1024 threads = 128 channels x 8 k-eighths, one chain per block,
// 128 blocks (16 waves = 4/SIMD). Thread (c,p) holds Whh rows {c,128+c,
// 256+c} over k-eighth p = 12 float4 = 48 floats. With __launch_bounds__
// (1024,4) the VGPR budget is 128/wave, so 48+overhead fits with slack ->
// residency is trivially the allocator's cheapest option (v1/v5/v6 needed
// 96-128 floats and the allocator streamed them from L2/AGPRs instead,
// pinning the kernel at ~103us).
// Reduce: quad_sum (DPP xor1+xor2) + __shfl_xor(,4) across the 8 p-lanes.
// LDS h reads rotated by p within each eighth -> worst 2-way bank alias
// (free, m136); same-p cross-channel reads broadcast.
// ---------------------------------------------------------------------------
__device__ __forceinline__ float sigm(float x) { return 1.f / (1.f + __expf(-x)); }
__device__ __forceinline__ float tanh_f(float x) { return 1.f - 2.f / (1.f + __expf(2.f * x)); }

__device__ __forceinline__ float dpp_xor1(float x) {
    return __builtin_bit_cast(float,
        __builtin_amdgcn_mov_dpp(__builtin_bit_cast(int, x), 0xB1, 0xF, 0xF, true));
}
__device__ __forceinline__ float dpp_xor2(float x) {
    return __builtin_bit_cast(float,
        __builtin_amdgcn_mov_dpp(__builtin_bit_cast(int, x), 0x4E, 0xF, 0xF, true));
}
__device__ __forceinline__ float quad_sum(float x) {
    x += dpp_xor1(x);
    x += dpp_xor2(x);
    return x;   // all 4 lanes of the quad hold the quad sum
}

__global__ __launch_bounds__(1024, 4)
void gru_scan(const float* __restrict__ gi_f,
              const float* __restrict__ gi_b,
              const float* __restrict__ Whh_f,
              const float* __restrict__ Whh_b,
              const float* __restrict__ bhh_f,
              const float* __restrict__ bhh_b,
              float* __restrict__ pooled) {
    const int tid = threadIdx.x;
    const int c   = tid >> 3;     // channel 0..127
    const int p   = tid & 7;      // k-eighth 0..7
    const int dir = blockIdx.x & 1;
    const int b   = blockIdx.x >> 1;
    const float* gi  = dir ? gi_b  : gi_f;
    const float* Whh = dir ? Whh_b : Whh_f;
    const float* bhh = dir ? bhh_b : bhh_f;

    __shared__ __align__(16) float hbuf[2][128];

    // 12 float4 weights: rows {c,128+c,256+c}, k-eighth p (4 f4 chunks),
    // chunk order rotated by p: slot i <-> global f4 chunk p*4 + ((i+p)&3)
    float4 w[3][4];
    const float4* wf4 = (const float4*)Whh;
    #pragma unroll
    for (int r = 0; r < 3; ++r)
        #pragma unroll
        for (int i = 0; i < 4; ++i)
            w[r][i] = wf4[(size_t)(r * 128 + c) * 32 + p * 4 + ((i + p) & 3)];

    float bh_r = 0.f, bh_z = 0.f, bh_n = 0.f;
    if (p == 0) { bh_r = bhh[c]; bh_z = bhh[128 + c]; bh_n = bhh[256 + c]; }

    float hold = 0.f, m = -INFINITY;
    if (tid < 128) hbuf[0][tid] = 0.f;

    // prefetch gi for steps 0 and 1 (p==0 lanes only)
    float g0r = 0.f, g0z = 0.f, g0n = 0.f, g1r = 0.f, g1z = 0.f, g1n = 0.f;
    if (p == 0) {
        const float* row0 = gi + ((size_t)b * LL + (dir ? LL - 1 : 0)) * 384;
        g0r = row0[c]; g0z = row0[128 + c]; g0n = row0[256 + c];
        const float* row1 = gi + ((size_t)b * LL + (dir ? LL - 2 : 1)) * 384;
        g1r = row1[c]; g1z = row1[128 + c]; g1n = row1[256 + c];
    }
    __syncthreads();   // publish hbuf[0]

    for (int s = 0; s < LL; ++s) {
        const int cur = s & 1;
        // prefetch gi for step s+2
        float g2r = 0.f, g2z = 0.f, g2n = 0.f;
        if (p == 0 && s + 2 < LL) {
            const int t2 = dir ? (LL - 3 - s) : (s + 2);
            const float* row = gi + ((size_t)b * LL + t2) * 384;
            g2r = row[c]; g2z = row[128 + c]; g2n = row[256 + c];
        }

        // partial matvec over this thread's k-eighth, rotated chunk order
        const float4* hq = (const float4*)hbuf[cur];
        float a0 = 0.f, a1 = 0.f, a2 = 0.f;
        #pragma unroll
        for (int i = 0; i < 4; ++i) {
            const float4 hv = hq[p * 4 + ((i + p) & 3)];
            a0 += w[0][i].x * hv.x + w[0][i].y * hv.y + w[0][i].z * hv.z + w[0][i].w * hv.w;
            a1 += w[1][i].x * hv.x + w[1][i].y * hv.y + w[1][i].z * hv.z + w[1][i].w * hv.w;
            a2 += w[2][i].x * hv.x + w[2][i].y * hv.y + w[2][i].z * hv.z + w[2][i].w * hv.w;
        }
        // reduce across the 8 p-lanes: quad (xor1+xor2 DPP) then xor4 shuffle
        a0 = quad_sum(a0); a1 = quad_sum(a1); a2 = quad_sum(a2);
        a0 += __shfl_xor(a0, 4, 64);
        a1 += __shfl_xor(a1, 4, 64);
        a2 += __shfl_xor(a2, 4, 64);

        if (p == 0) {
            const float r = sigm(g0r + a0 + bh_r);
            const float z = sigm(g0z + a1 + bh_z);
            const float n = tanh_f(g0n + r * (a2 + bh_n));
            const float hn = (1.f - z) * n + z * hold;
            hold = hn;
            m = fmaxf(m, hn);
            hbuf[cur ^ 1][c] = hn;
        }
        g0r = g1r; g0z = g1z; g0n = g1n;
        g1r = g2r; g1z = g2z; g1n = g2n;
        __syncthreads();   // publish hbuf[cur^1] for next step
    }
    if (p == 0) pooled[((size_t)b * 2 + dir) * 128 + c] = m;
}

// ---------------------------------------------------------------------------
// Output head: out[b,o] = pooled[b,:]·Wout[o,:] + bout[o]   (64 x 104 x 256)
// ---------------------------------------------------------------------------
__global__ __launch_bounds__(128) void out_head(const float* __restrict__ pooled,
                                                const float* __restrict__ Wout,
                                                const float* __restrict__ bout,
                                                float* __restrict__ out) {
    __shared__ __align__(16) float pbuf[256];
    const int b = blockIdx.x, o = threadIdx.x;
    if (o < 64) ((float4*)pbuf)[o] = ((const float4*)(pooled + (size_t)b * 256))[o];
    __syncthreads();
    if (o < NLBL) {
        float acc = bout[o];
        const float4* wf4 = (const float4*)(Wout + (size_t)o * 256);
        const float4* pf4 = (const float4*)pbuf;
        #pragma unroll 8
        for (int q = 0; q < 64; ++q) {
            float4 wv = wf4[q], pv = pf4[q];
            acc += wv.x * pv.x + wv.y * pv.y + wv.z * pv.z + wv.w * pv.w;
        }
        out[(size_t)b * NLBL + o] = acc;
    }
}

// ---------------------------------------------------------------------------
extern "C" void kernel_launch(void* const* d_in, const int* in_sizes, int n_in,
                              void* d_out, int out_size, void* d_ws, size_t ws_size,
                              hipStream_t stream) {
    const int*   tokens = (const int*)  d_in[0];
    const float* emb    = (const float*)d_in[1];
    const float* Wc_w   = (const float*)d_in[2];
    const float* Wc_b   = (const float*)d_in[3];
    const float* Wih_f  = (const float*)d_in[4];
    const float* Whh_f  = (const float*)d_in[5];
    const float* bih_f  = (const float*)d_in[6];
    const float* bhh_f  = (const float*)d_in[7];
    const float* Wih_b  = (const float*)d_in[8];
    const float* Whh_b  = (const float*)d_in[9];
    const float* bih_b  = (const float*)d_in[10];
    const float* bhh_b  = (const float*)d_in[11];
    const float* Wout   = (const float*)d_in[12];
    const float* bout   = (const float*)d_in[13];
    float* out = (float*)d_out;
    float* ws  = (float*)d_ws;

    float* Wemb = ws;                                   // 50000*128
    float* enc  = Wemb + (size_t)VV * 128;              // 8192*128
    float* gi_f = enc  + (size_t)BB * LL * 128;         // 8192*384
    float* gi_b = gi_f + (size_t)BB * LL * 384;         // 8192*384
    float* pool = gi_b + (size_t)BB * LL * 384;         // 64*256

    // 1. projected embedding table: Wemb = emb @ Wc_w^T  (1.64 GFLOP)
    gemm128<false><<<dim3(782, 1, 1), 256, 0, stream>>>(
        emb, Wc_w, Wc_w, nullptr, nullptr, Wemb, Wemb, VV, 128);
    // 2. gather + tree-sum + node-max -> encodes (8192 x 128)
    tree_encode<<<dim3(4096), 256, 0, stream>>>(tokens, Wemb, Wc_b, enc);
    // 3. input gates, both directions in ONE dispatch (z selects dir)
    gemm128<true><<<dim3(128, 3, 2), 256, 0, stream>>>(
        enc, Wih_f, Wih_b, bih_f, bih_b, gi_f, gi_b, BB * LL, 384);
    // 4. sequential GRU scans: 128 chains (64 b x 2 dir) -> 128 blocks
    gru_scan<<<dim3(128), 1024, 0, stream>>>(gi_f, gi_b, Whh_f, Whh_b, bhh_f, bhh_b, pool);
    // 5. output head
    out_head<<<dim3(64), 128, 0, stream>>>(pool, Wout, bout, out);
}

// Round 10
// 309.488 us; speedup vs baseline: 1.0130x; 1.0130x over previous
//
#include <hip/hip_runtime.h>
#include <hip/hip_bf16.h>
#include <math.h>

// Problem constants (from reference)
#define NN   31      // tree nodes
#define VV   50000   // vocab
#define EE   128     // embed = enc = H = 128
#define HH   128
#define BB   64
#define LL   128
#define NLBL 104

// ---------------------------------------------------------------------------
// Generic fp32 GEMM: C[M,N] = A[M,128] * B[N,128]^T (+ bias[N])
// Tile 64x128, 256 threads, K split in 2 halves of 64 so LDS stays < 64KB.
// gridDim.z indexes a (B, bias, C) set -> fuses sibling GEMMs sharing A.
// ---------------------------------------------------------------------------
template <bool BIAS>
__global__ __launch_bounds__(256, 2) void gemm128(const float* __restrict__ A,
                                                  const float* __restrict__ B0,
                                                  const float* __restrict__ B1,
                                                  const float* __restrict__ bias0,
                                                  const float* __restrict__ bias1,
                                                  float* __restrict__ C0,
                                                  float* __restrict__ C1,
                                                  int M, int N) {
    const float* Bm  = blockIdx.z ? B1 : B0;
    const float* bias = blockIdx.z ? bias1 : bias0;
    float* C = blockIdx.z ? C1 : C0;

    __shared__ float4 As[64 * 17];
    __shared__ float4 Bs[128 * 17];
    const int tid = threadIdx.x;
    const int m0 = blockIdx.x * 64;
    const int n0 = blockIdx.y * 128;
    const float4* Af4 = (const float4*)A;
    const float4* Bf4 = (const float4*)Bm;

    const int r0 = (tid >> 4) * 4;
    const int cb = tid & 15;
    float acc[4][8] = {};

    for (int kk = 0; kk < 2; ++kk) {
        for (int f = tid; f < 128 * 16; f += 256) {
            int r = f >> 4, e = f & 15;
            Bs[r * 17 + e] = Bf4[(size_t)(n0 + r) * 32 + kk * 16 + e];
        }
        for (int f = tid; f < 64 * 16; f += 256) {
            int r = f >> 4, e = f & 15;
            float4 v = make_float4(0.f, 0.f, 0.f, 0.f);
            if (m0 + r < M) v = Af4[(size_t)(m0 + r) * 32 + kk * 16 + e];
            As[r * 17 + e] = v;
        }
        __syncthreads();
        #pragma unroll
        for (int e = 0; e < 16; ++e) {
            float4 a[4], b[8];
            #pragma unroll
            for (int i = 0; i < 4; ++i) a[i] = As[(r0 + i) * 17 + e];
            #pragma unroll
            for (int j = 0; j < 8; ++j) b[j] = Bs[(cb + j * 16) * 17 + e];
            #pragma unroll
            for (int i = 0; i < 4; ++i) {
                #pragma unroll
                for (int j = 0; j < 8; ++j) {
                    acc[i][j] += a[i].x * b[j].x;
                    acc[i][j] += a[i].y * b[j].y;
                    acc[i][j] += a[i].z * b[j].z;
                    acc[i][j] += a[i].w * b[j].w;
                }
            }
        }
        __syncthreads();
    }

    #pragma unroll
    for (int i = 0; i < 4; ++i) {
        int row = m0 + r0 + i;
        if (row < M) {
            #pragma unroll
            for (int j = 0; j < 8; ++j) {
                int col = n0 + cb + j * 16;
                float v = acc[i][j];
                if (BIAS) v += bias[col];
                C[(size_t)row * N + col] = v;
            }
        }
    }
}

// ---------------------------------------------------------------------------
// Tree encode: gather 31 projected rows, heap-sum in regs, node-max.
// ---------------------------------------------------------------------------
__global__ __launch_bounds__(256) void tree_encode(const int* __restrict__ tok,
                                                   const float* __restrict__ Wemb,
                                                   const float* __restrict__ Wcb,
                                                   float* __restrict__ enc) {
    __shared__ int st[2][NN];
    const int tid = threadIdx.x;
    const int p = tid >> 7;
    const int c = tid & 127;
    const int bl = blockIdx.x * 2;
    if (tid < 2 * NN) {
        int pp = tid / NN, jj = tid - pp * NN;
        st[pp][jj] = tok[(size_t)(bl + pp) * NN + jj];
    }
    __syncthreads();

    float v[NN];
    #pragma unroll
    for (int j = 0; j < NN; ++j)
        v[j] = Wemb[(size_t)st[p][j] * 128 + c];
    #pragma unroll
    for (int i = 14; i >= 0; --i)
        v[i] += v[2 * i + 1] + v[2 * i + 2];

    const float wb = Wcb[c];
    float m = v[0] + 31.f * wb;
    #pragma unroll
    for (int i = 1; i <= 2; ++i)  m = fmaxf(m, v[i] + 15.f * wb);
    #pragma unroll
    for (int i = 3; i <= 6; ++i)  m = fmaxf(m, v[i] + 7.f * wb);
    #pragma unroll
    for (int i = 7; i <= 14; ++i) m = fmaxf(m, v[i] + 3.f * wb);
    #pragma unroll
    for (int i = 15; i <= 30; ++i) m = fmaxf(m, v[i] + wb);

    enc[(size_t)(bl + p) * 128 + c] = m;
}

// ---------------------------------------------------------------------------
// GRU scan v9 = v6 structure + VOLATILE weight loads.
// Root cause finally identified: weight loads from const __restrict__ memory
// are marked invariant -> LLVM's RA REMATERIALIZES (re-issues) them inside
// the step loop to minimize register pressure. Evidence: VGPR_Count 116/68/
// 88/44 across v2/v5/v6/v8 -- always below the weight footprint, with active
// -CU VALUBusy ~82-92% and ~395 VALU instrs/wave/step vs ~150 ideal (v6
// arithmetic). The kernel was VALU-overhead-bound on remat'd loads, not
// L2-BW-bound. volatile loads CANNOT be rematerialized/sunk/duplicated; the
// RA must keep the values live, and with __launch_bounds__(512,2) (256-reg
// budget vs ~136 needed) spilling is never preferable.
// Scalar volatile loads (volatile float4 copy doesn't compile); one-time
// cost of 96 scalar vs 24 vector loads is negligible.
// Layout (proven v5/v6): 512 thr = 128 channels x 4 k-quarters, one chain
// per block, 128 blocks. Rotated k-chunk order -> conflict-free LDS reads
// (SQ_LDS_BANK_CONFLICT was 0 in v6). Depth-2 gi prefetch, __syncthreads.
// ---------------------------------------------------------------------------
__device__ __forceinline__ float sigm(float x) { return 1.f / (1.f + __expf(-x)); }
__device__ __forceinline__ float tanh_f(float x) { return 1.f - 2.f / (1.f + __expf(2.f * x)); }

__device__ __forceinline__ float dpp_xor1(float x) {
    return __builtin_bit_cast(float,
        __builtin_amdgcn_mov_dpp(__builtin_bit_cast(int, x), 0xB1, 0xF, 0xF, true));
}
__device__ __forceinline__ float dpp_xor2(float x) {
    return __builtin_bit_cast(float,
        __builtin_amdgcn_mov_dpp(__builtin_bit_cast(int, x), 0x4E, 0xF, 0xF, true));
}
__device__ __forceinline__ float quad_sum(float x) {
    x += dpp_xor1(x);
    x += dpp_xor2(x);
    return x;   // all 4 lanes of the quad hold the full sum
}

__global__ __launch_bounds__(512, 2)
void gru_scan(const float* __restrict__ gi_f,
              const float* __restrict__ gi_b,
              const float* __restrict__ Whh_f,
              const float* __restrict__ Whh_b,
              const float* __restrict__ bhh_f,
              const float* __restrict__ bhh_b,
              float* __restrict__ pooled) {
    const int tid = threadIdx.x;
    const int c   = tid >> 2;     // channel 0..127
    const int p   = tid & 3;      // k-quarter 0..3
    const int dir = blockIdx.x & 1;
    const int b   = blockIdx.x >> 1;
    const float* gi  = dir ? gi_b  : gi_f;
    const float* Whh = dir ? Whh_b : Whh_f;
    const float* bhh = dir ? bhh_b : bhh_f;

    __shared__ __align__(16) float hbuf[2][128];

    // weights: rows {c,128+c,256+c}, k-quarter p as 8 f4 chunks, chunk order
    // rotated by 2p. VOLATILE loads -> not rematerializable -> must stay in
    // VGPRs across the loop (the whole point of v9).
    float4 w[3][8];
    {
        const volatile float* wv = (const volatile float*)Whh;
        #pragma unroll
        for (int r = 0; r < 3; ++r)
            #pragma unroll
            for (int i = 0; i < 8; ++i) {
                const size_t base =
                    ((size_t)(r * 128 + c) * 32 + p * 8 + ((i + 2 * p) & 7)) * 4;
                w[r][i].x = wv[base + 0];
                w[r][i].y = wv[base + 1];
                w[r][i].z = wv[base + 2];
                w[r][i].w = wv[base + 3];
            }
    }

    float bh_r = 0.f, bh_z = 0.f, bh_n = 0.f;
    if (p == 0) { bh_r = bhh[c]; bh_z = bhh[128 + c]; bh_n = bhh[256 + c]; }

    float hold = 0.f, m = -INFINITY;
    if (tid < 128) hbuf[0][tid] = 0.f;

    // prefetch gi for steps 0 and 1 (p==0 lanes only)
    float g0r = 0.f, g0z = 0.f, g0n = 0.f, g1r = 0.f, g1z = 0.f, g1n = 0.f;
    if (p == 0) {
        const float* row0 = gi + ((size_t)b * LL + (dir ? LL - 1 : 0)) * 384;
        g0r = row0[c]; g0z = row0[128 + c]; g0n = row0[256 + c];
        const float* row1 = gi + ((size_t)b * LL + (dir ? LL - 2 : 1)) * 384;
        g1r = row1[c]; g1z = row1[128 + c]; g1n = row1[256 + c];
    }
    __syncthreads();   // publish hbuf[0]

    for (int s = 0; s < LL; ++s) {
        const int cur = s & 1;
        // prefetch gi for step s+2
        float g2r = 0.f, g2z = 0.f, g2n = 0.f;
        if (p == 0 && s + 2 < LL) {
            const int t2 = dir ? (LL - 3 - s) : (s + 2);
            const float* row = gi + ((size_t)b * LL + t2) * 384;
            g2r = row[c]; g2z = row[128 + c]; g2n = row[256 + c];
        }

        // partial matvec over this thread's k-quarter, rotated chunk order
        const float4* hq = (const float4*)hbuf[cur];
        float a0 = 0.f, a1 = 0.f, a2 = 0.f;
        #pragma unroll
        for (int i = 0; i < 8; ++i) {
            const float4 hv = hq[p * 8 + ((i + 2 * p) & 7)];
            a0 += w[0][i].x * hv.x + w[0][i].y * hv.y + w[0][i].z * hv.z + w[0][i].w * hv.w;
            a1 += w[1][i].x * hv.x + w[1][i].y * hv.y + w[1][i].z * hv.z + w[1][i].w * hv.w;
            a2 += w[2][i].x * hv.x + w[2][i].y * hv.y + w[2][i].z * hv.z + w[2][i].w * hv.w;
        }
        a0 = quad_sum(a0); a1 = quad_sum(a1); a2 = quad_sum(a2);

        if (p == 0) {
            const float r = sigm(g0r + a0 + bh_r);
            const float z = sigm(g0z + a1 + bh_z);
            const float n = tanh_f(g0n + r * (a2 + bh_n));
            const float hn = (1.f - z) * n + z * hold;
            hold = hn;
            m = fmaxf(m, hn);
            hbuf[cur ^ 1][c] = hn;
        }
        g0r = g1r; g0z = g1z; g0n = g1n;
        g1r = g2r; g1z = g2z; g1n = g2n;
        __syncthreads();   // publish hbuf[cur^1] for next step
    }
    if (p == 0) pooled[((size_t)b * 2 + dir) * 128 + c] = m;
}

// ---------------------------------------------------------------------------
// Output head: out[b,o] = pooled[b,:]·Wout[o,:] + bout[o]   (64 x 104 x 256)
// ---------------------------------------------------------------------------
__global__ __launch_bounds__(128) void out_head(const float* __restrict__ pooled,
                                                const float* __restrict__ Wout,
                                                const float* __restrict__ bout,
                                                float* __restrict__ out) {
    __shared__ __align__(16) float pbuf[256];
    const int b = blockIdx.x, o = threadIdx.x;
    if (o < 64) ((float4*)pbuf)[o] = ((const float4*)(pooled + (size_t)b * 256))[o];
    __syncthreads();
    if (o < NLBL) {
        float acc = bout[o];
        const float4* wf4 = (const float4*)(Wout + (size_t)o * 256);
        const float4* pf4 = (const float4*)pbuf;
        #pragma unroll 8
        for (int q = 0; q < 64; ++q) {
            float4 wv = wf4[q], pv = pf4[q];
            acc += wv.x * pv.x + wv.y * pv.y + wv.z * pv.z + wv.w * pv.w;
        }
        out[(size_t)b * NLBL + o] = acc;
    }
}

// ---------------------------------------------------------------------------
extern "C" void kernel_launch(void* const* d_in, const int* in_sizes, int n_in,
                              void* d_out, int out_size, void* d_ws, size_t ws_size,
                              hipStream_t stream) {
    const int*   tokens = (const int*)  d_in[0];
    const float* emb    = (const float*)d_in[1];
    const float* Wc_w   = (const float*)d_in[2];
    const float* Wc_b   = (const float*)d_in[3];
    const float* Wih_f  = (const float*)d_in[4];
    const float* Whh_f  = (const float*)d_in[5];
    const float* bih_f  = (const float*)d_in[6];
    const float* bhh_f  = (const float*)d_in[7];
    const float* Wih_b  = (const float*)d_in[8];
    const float* Whh_b  = (const float*)d_in[9];
    const float* bih_b  = (const float*)d_in[10];
    const float* bhh_b  = (const float*)d_in[11];
    const float* Wout   = (const float*)d_in[12];
    const float* bout   = (const float*)d_in[13];
    float* out = (float*)d_out;
    float* ws  = (float*)d_ws;

    float* Wemb = ws;                                   // 50000*128
    float* enc  = Wemb + (size_t)VV * 128;              // 8192*128
    float* gi_f = enc  + (size_t)BB * LL * 128;         // 8192*384
    float* gi_b = gi_f + (size_t)BB * LL * 384;         // 8192*384
    float* pool = gi_b + (size_t)BB * LL * 384;         // 64*256

    // 1. projected embedding table: Wemb = emb @ Wc_w^T  (1.64 GFLOP)
    gemm128<false><<<dim3(782, 1, 1), 256, 0, stream>>>(
        emb, Wc_w, Wc_w, nullptr, nullptr, Wemb, Wemb, VV, 128);
    // 2. gather + tree-sum + node-max -> encodes (8192 x 128)
    tree_encode<<<dim3(4096), 256, 0, stream>>>(tokens, Wemb, Wc_b, enc);
    // 3. input gates, both directions in ONE dispatch (z selects dir)
    gemm128<true><<<dim3(128, 3, 2), 256, 0, stream>>>(
        enc, Wih_f, Wih_b, bih_f, bih_b, gi_f, gi_b, BB * LL, 384);
    // 4. sequential GRU scans: 128 chains (64 b x 2 dir) -> 128 blocks
    gru_scan<<<dim3(128), 512, 0, stream>>>(gi_f, gi_b, Whh_f, Whh_b, bhh_f, bhh_b, pool);
    // 5. output head
    out_head<<<dim3(64), 128, 0, stream>>>(pool, Wout, bout, out);
}

// Round 11
// 293.157 us; speedup vs baseline: 1.0694x; 1.0557x over previous
//
#include <hip/hip_runtime.h>
#include <hip/hip_bf16.h>
#include <math.h>

// Problem constants (from reference)
#define NN   31      // tree nodes
#define VV   50000   // vocab
#define EE   128     // embed = enc = H = 128
#define HH   128
#define BB   64
#define LL   128
#define NLBL 104

// ---------------------------------------------------------------------------
// Generic fp32 GEMM: C[M,N] = A[M,128] * B[N,128]^T (+ bias[N])
// Tile 64x128, 256 threads, K split in 2 halves of 64 so LDS stays < 64KB.
// gridDim.z indexes a (B, bias, C) set -> fuses sibling GEMMs sharing A.
// ---------------------------------------------------------------------------
template <bool BIAS>
__global__ __launch_bounds__(256, 2) void gemm128(const float* __restrict__ A,
                                                  const float* __restrict__ B0,
                                                  const float* __restrict__ B1,
                                                  const float* __restrict__ bias0,
                                                  const float* __restrict__ bias1,
                                                  float* __restrict__ C0,
                                                  float* __restrict__ C1,
                                                  int M, int N) {
    const float* Bm  = blockIdx.z ? B1 : B0;
    const float* bias = blockIdx.z ? bias1 : bias0;
    float* C = blockIdx.z ? C1 : C0;

    __shared__ float4 As[64 * 17];
    __shared__ float4 Bs[128 * 17];
    const int tid = threadIdx.x;
    const int m0 = blockIdx.x * 64;
    const int n0 = blockIdx.y * 128;
    const float4* Af4 = (const float4*)A;
    const float4* Bf4 = (const float4*)Bm;

    const int r0 = (tid >> 4) * 4;
    const int cb = tid & 15;
    float acc[4][8] = {};

    for (int kk = 0; kk < 2; ++kk) {
        for (int f = tid; f < 128 * 16; f += 256) {
            int r = f >> 4, e = f & 15;
            Bs[r * 17 + e] = Bf4[(size_t)(n0 + r) * 32 + kk * 16 + e];
        }
        for (int f = tid; f < 64 * 16; f += 256) {
            int r = f >> 4, e = f & 15;
            float4 v = make_float4(0.f, 0.f, 0.f, 0.f);
            if (m0 + r < M) v = Af4[(size_t)(m0 + r) * 32 + kk * 16 + e];
            As[r * 17 + e] = v;
        }
        __syncthreads();
        #pragma unroll
        for (int e = 0; e < 16; ++e) {
            float4 a[4], b[8];
            #pragma unroll
            for (int i = 0; i < 4; ++i) a[i] = As[(r0 + i) * 17 + e];
            #pragma unroll
            for (int j = 0; j < 8; ++j) b[j] = Bs[(cb + j * 16) * 17 + e];
            #pragma unroll
            for (int i = 0; i < 4; ++i) {
                #pragma unroll
                for (int j = 0; j < 8; ++j) {
                    acc[i][j] += a[i].x * b[j].x;
                    acc[i][j] += a[i].y * b[j].y;
                    acc[i][j] += a[i].z * b[j].z;
                    acc[i][j] += a[i].w * b[j].w;
                }
            }
        }
        __syncthreads();
    }

    #pragma unroll
    for (int i = 0; i < 4; ++i) {
        int row = m0 + r0 + i;
        if (row < M) {
            #pragma unroll
            for (int j = 0; j < 8; ++j) {
                int col = n0 + cb + j * 16;
                float v = acc[i][j];
                if (BIAS) v += bias[col];
                C[(size_t)row * N + col] = v;
            }
        }
    }
}

// ---------------------------------------------------------------------------
// Tree encode: gather 31 projected rows, heap-sum in regs, node-max.
// ---------------------------------------------------------------------------
__global__ __launch_bounds__(256) void tree_encode(const int* __restrict__ tok,
                                                   const float* __restrict__ Wemb,
                                                   const float* __restrict__ Wcb,
                                                   float* __restrict__ enc) {
    __shared__ int st[2][NN];
    const int tid = threadIdx.x;
    const int p = tid >> 7;
    const int c = tid & 127;
    const int bl = blockIdx.x * 2;
    if (tid < 2 * NN) {
        int pp = tid / NN, jj = tid - pp * NN;
        st[pp][jj] = tok[(size_t)(bl + pp) * NN + jj];
    }
    __syncthreads();

    float v[NN];
    #pragma unroll
    for (int j = 0; j < NN; ++j)
        v[j] = Wemb[(size_t)st[p][j] * 128 + c];
    #pragma unroll
    for (int i = 14; i >= 0; --i)
        v[i] += v[2 * i + 1] + v[2 * i + 2];

    const float wb = Wcb[c];
    float m = v[0] + 31.f * wb;
    #pragma unroll
    for (int i = 1; i <= 2; ++i)  m = fmaxf(m, v[i] + 15.f * wb);
    #pragma unroll
    for (int i = 3; i <= 6; ++i)  m = fmaxf(m, v[i] + 7.f * wb);
    #pragma unroll
    for (int i = 7; i <= 14; ++i) m = fmaxf(m, v[i] + 3.f * wb);
    #pragma unroll
    for (int i = 15; i <= 30; ++i) m = fmaxf(m, v[i] + wb);

    enc[(size_t)(bl + p) * 128 + c] = m;
}

// ---------------------------------------------------------------------------
// GRU scan v10 = v6 structure + LOOP-CARRIED weights (in-loop opaque pin).
// Saga: the RA rematerializes invariant weight loads into the step loop at
// ANY footprint (v2:116, v5:68, v6:88+prologue-pin, v8:44 regs), making the
// kernel L2-BW-bound (~31 TB/s on 3.2 GB of re-reads, 102us). volatile (v9)
// outlawed remat -> RA spilled to scratch instead (68 regs, 129us). What the
// RA *does* keep resident: LOOP-CARRIED values (GEMM accumulators at 164+64
// regs) -- spilling a per-iteration-redefined value costs a store+load every
// iteration, which its cost model rejects.
// So: empty asm volatile "+v" on every weight component INSIDE the step loop
// (after use). Each iteration redefines w -> remat across iterations is
// impossible (def is the asm, not the load); spill now costs 24 st+ld/iter.
// Zero instructions emitted. Prologue-pin (v6) failed because the value
// stayed invariant ACROSS the loop; this is the mechanistic difference.
// Layout (v6, proven): 512 thr = 128 channels x 4 k-quarters, 1 chain/block,
// 128 blocks. Rotation 2p: lanes' 4 bank-quads distinct per slot -> 0
// conflicts (measured). Depth-2 gi prefetch, __syncthreads.
// Falsifiable: VGPR_Count >= 130 and dur 40-55us, else the register path is
// dead and v11 goes MFMA split-bf16.
// ---------------------------------------------------------------------------
__device__ __forceinline__ float sigm(float x) { return 1.f / (1.f + __expf(-x)); }
__device__ __forceinline__ float tanh_f(float x) { return 1.f - 2.f / (1.f + __expf(2.f * x)); }

__device__ __forceinline__ float dpp_xor1(float x) {
    return __builtin_bit_cast(float,
        __builtin_amdgcn_mov_dpp(__builtin_bit_cast(int, x), 0xB1, 0xF, 0xF, true));
}
__device__ __forceinline__ float dpp_xor2(float x) {
    return __builtin_bit_cast(float,
        __builtin_amdgcn_mov_dpp(__builtin_bit_cast(int, x), 0x4E, 0xF, 0xF, true));
}
__device__ __forceinline__ float quad_sum(float x) {
    x += dpp_xor1(x);
    x += dpp_xor2(x);
    return x;   // all 4 lanes of the quad hold the full sum
}

__global__ __launch_bounds__(512, 2)
void gru_scan(const float* __restrict__ gi_f,
              const float* __restrict__ gi_b,
              const float* __restrict__ Whh_f,
              const float* __restrict__ Whh_b,
              const float* __restrict__ bhh_f,
              const float* __restrict__ bhh_b,
              float* __restrict__ pooled) {
    const int tid = threadIdx.x;
    const int c   = tid >> 2;     // channel 0..127
    const int p   = tid & 3;      // k-quarter 0..3
    const int dir = blockIdx.x & 1;
    const int b   = blockIdx.x >> 1;
    const float* gi  = dir ? gi_b  : gi_f;
    const float* Whh = dir ? Whh_b : Whh_f;
    const float* bhh = dir ? bhh_b : bhh_f;

    __shared__ __align__(16) float hbuf[2][128];

    // weights: rows {c,128+c,256+c}, k-quarter p as 8 f4 chunks, chunk order
    // rotated by 2p (conflict-free broadcast LDS h reads, measured 0 in v6)
    float4 w[3][8];
    const float4* wf4 = (const float4*)Whh;
    #pragma unroll
    for (int r = 0; r < 3; ++r)
        #pragma unroll
        for (int i = 0; i < 8; ++i)
            w[r][i] = wf4[(size_t)(r * 128 + c) * 32 + p * 8 + ((i + 2 * p) & 7)];

    float bh_r = 0.f, bh_z = 0.f, bh_n = 0.f;
    if (p == 0) { bh_r = bhh[c]; bh_z = bhh[128 + c]; bh_n = bhh[256 + c]; }

    float hold = 0.f, m = -INFINITY;
    if (tid < 128) hbuf[0][tid] = 0.f;

    // prefetch gi for steps 0 and 1 (p==0 lanes only)
    float g0r = 0.f, g0z = 0.f, g0n = 0.f, g1r = 0.f, g1z = 0.f, g1n = 0.f;
    if (p == 0) {
        const float* row0 = gi + ((size_t)b * LL + (dir ? LL - 1 : 0)) * 384;
        g0r = row0[c]; g0z = row0[128 + c]; g0n = row0[256 + c];
        const float* row1 = gi + ((size_t)b * LL + (dir ? LL - 2 : 1)) * 384;
        g1r = row1[c]; g1z = row1[128 + c]; g1n = row1[256 + c];
    }
    __syncthreads();   // publish hbuf[0]

    for (int s = 0; s < LL; ++s) {
        const int cur = s & 1;
        // prefetch gi for step s+2
        float g2r = 0.f, g2z = 0.f, g2n = 0.f;
        if (p == 0 && s + 2 < LL) {
            const int t2 = dir ? (LL - 3 - s) : (s + 2);
            const float* row = gi + ((size_t)b * LL + t2) * 384;
            g2r = row[c]; g2z = row[128 + c]; g2n = row[256 + c];
        }

        // partial matvec over this thread's k-quarter, rotated chunk order
        const float4* hq = (const float4*)hbuf[cur];
        float a0 = 0.f, a1 = 0.f, a2 = 0.f;
        #pragma unroll
        for (int i = 0; i < 8; ++i) {
            const float4 hv = hq[p * 8 + ((i + 2 * p) & 7)];
            a0 += w[0][i].x * hv.x + w[0][i].y * hv.y + w[0][i].z * hv.z + w[0][i].w * hv.w;
            a1 += w[1][i].x * hv.x + w[1][i].y * hv.y + w[1][i].z * hv.z + w[1][i].w * hv.w;
            a2 += w[2][i].x * hv.x + w[2][i].y * hv.y + w[2][i].z * hv.z + w[2][i].w * hv.w;
        }
        a0 = quad_sum(a0); a1 = quad_sum(a1); a2 = quad_sum(a2);

        if (p == 0) {
            const float r = sigm(g0r + a0 + bh_r);
            const float z = sigm(g0z + a1 + bh_z);
            const float n = tanh_f(g0n + r * (a2 + bh_n));
            const float hn = (1.f - z) * n + z * hold;
            hold = hn;
            m = fmaxf(m, hn);
            hbuf[cur ^ 1][c] = hn;
        }
        g0r = g1r; g0z = g1z; g0n = g1n;
        g1r = g2r; g1z = g2z; g1n = g2n;

        // LOOP-CARRIED PIN: redefine every weight reg each iteration (0-cost
        // empty asm). RA can no longer remat from the invariant load, and
        // spilling a per-iter-redefined value costs 24 st+ld per iteration.
        #pragma unroll
        for (int r2 = 0; r2 < 3; ++r2)
            #pragma unroll
            for (int i2 = 0; i2 < 8; ++i2)
                asm volatile("" : "+v"(w[r2][i2].x), "+v"(w[r2][i2].y),
                                  "+v"(w[r2][i2].z), "+v"(w[r2][i2].w));

        __syncthreads();   // publish hbuf[cur^1] for next step
    }
    if (p == 0) pooled[((size_t)b * 2 + dir) * 128 + c] = m;
}

// ---------------------------------------------------------------------------
// Output head: out[b,o] = pooled[b,:]·Wout[o,:] + bout[o]   (64 x 104 x 256)
// ---------------------------------------------------------------------------
__global__ __launch_bounds__(128) void out_head(const float* __restrict__ pooled,
                                                const float* __restrict__ Wout,
                                                const float* __restrict__ bout,
                                                float* __restrict__ out) {
    __shared__ __align__(16) float pbuf[256];
    const int b = blockIdx.x, o = threadIdx.x;
    if (o < 64) ((float4*)pbuf)[o] = ((const float4*)(pooled + (size_t)b * 256))[o];
    __syncthreads();
    if (o < NLBL) {
        float acc = bout[o];
        const float4* wf4 = (const float4*)(Wout + (size_t)o * 256);
        const float4* pf4 = (const float4*)pbuf;
        #pragma unroll 8
        for (int q = 0; q < 64; ++q) {
            float4 wv = wf4[q], pv = pf4[q];
            acc += wv.x * pv.x + wv.y * pv.y + wv.z * pv.z + wv.w * pv.w;
        }
        out[(size_t)b * NLBL + o] = acc;
    }
}

// ---------------------------------------------------------------------------
extern "C" void kernel_launch(void* const* d_in, const int* in_sizes, int n_in,
                              void* d_out, int out_size, void* d_ws, size_t ws_size,
                              hipStream_t stream) {
    const int*   tokens = (const int*)  d_in[0];
    const float* emb    = (const float*)d_in[1];
    const float* Wc_w   = (const float*)d_in[2];
    const float* Wc_b   = (const float*)d_in[3];
    const float* Wih_f  = (const float*)d_in[4];
    const float* Whh_f  = (const float*)d_in[5];
    const float* bih_f  = (const float*)d_in[6];
    const float* bhh_f  = (const float*)d_in[7];
    const float* Wih_b  = (const float*)d_in[8];
    const float* Whh_b  = (const float*)d_in[9];
    const float* bih_b  = (const float*)d_in[10];
    const float* bhh_b  = (const float*)d_in[11];
    const float* Wout   = (const float*)d_in[12];
    const float* bout   = (const float*)d_in[13];
    float* out = (float*)d_out;
    float* ws  = (float*)d_ws;

    float* Wemb = ws;                                   // 50000*128
    float* enc  = Wemb + (size_t)VV * 128;              // 8192*128
    float* gi_f = enc  + (size_t)BB * LL * 128;         // 8192*384
    float* gi_b = gi_f + (size_t)BB * LL * 384;         // 8192*384
    float* pool = gi_b + (size_t)BB * LL * 384;         // 64*256

    // 1. projected embedding table: Wemb = emb @ Wc_w^T  (1.64 GFLOP)
    gemm128<false><<<dim3(782, 1, 1), 256, 0, stream>>>(
        emb, Wc_w, Wc_w, nullptr, nullptr, Wemb, Wemb, VV, 128);
    // 2. gather + tree-sum + node-max -> encodes (8192 x 128)
    tree_encode<<<dim3(4096), 256, 0, stream>>>(tokens, Wemb, Wc_b, enc);
    // 3. input gates, both directions in ONE dispatch (z selects dir)
    gemm128<true><<<dim3(128, 3, 2), 256, 0, stream>>>(
        enc, Wih_f, Wih_b, bih_f, bih_b, gi_f, gi_b, BB * LL, 384);
    // 4. sequential GRU scans: 128 chains (64 b x 2 dir) -> 128 blocks
    gru_scan<<<dim3(128), 512, 0, stream>>>(gi_f, gi_b, Whh_f, Whh_b, bhh_f, bhh_b, pool);
    // 5. output head
    out_head<<<dim3(64), 128, 0, stream>>>(pool, Wout, bout, out);
}